// Round 12
// baseline (245.347 us; speedup 1.0000x reference)
//
#include <hip/hip_runtime.h>

// ---------------------------------------------------------------------------
// VisionEncoder: project tokens to hidden dim FIRST (pooling commutes with the
// linear map), then 2D summed-area table in 128-dim space, then fused
// gather + LayerNorm + ReLU + GEMM2.  Output FP32 (R9). Pipeline verified on
// safe rows end-to-end (R11 probe).
//
// Round-12 coordinate semantics: V4 — XLA-CPU strength reduction of division
// by a constant into multiply-by-reciprocal:
//     r  = fl32(1/W)            (constant-folded, correctly rounded)
//     q  = fl32(x * r)
//     p  = fl32(q * npw)
//     px = trunc(p)
// Rationale: R11 proved the mismatch is confined to multiple-of-14 coords;
// faithful-f32 (V1), f64 (V2), and f32div+exact-mul (V3) are all ruled out
// by distinct failures; a faithful numpy port would be V1 (numpy 1.x) or V2
// (NEP-50) => "ref=np" is the reference run through JAX/XLA on CPU, whose
// AlgebraicSimplifier rewrites x/const -> x*(1/const). Emulated bit-exactly
// via f64 (each f32 op correctly rounded) in a noinline+optnone helper.
// ---------------------------------------------------------------------------

#define HD 128  // hidden dim (verified: in_sizes[5] == 128)

__device__ __forceinline__ int decode_dim(const int* p, int fallback) {
    if (p == nullptr) return fallback;
    int vi = *p;
    if (vi >= 1 && vi <= 1000000) return vi;
    float vf = __int_as_float(vi);
    if (vf >= 1.0f && vf <= 1000000.0f) return (int)vf;
    return fallback;
}

// V4: trunc( fl32( fl32(x * fl32(1/W)) * n ) ), every f32 op correctly
// rounded, emulated through f64 (products of f32 values are exact in f64, so
// each cast is a single correct rounding; 1/W via f64 div then cast is the
// CR f32 reciprocal — 1/1036 is far from any f32 rounding boundary).
// optnone: forbid any fast-math/contraction rewrite.
__attribute__((noinline, optnone))
__device__ int coord_map(int x, int W, int n) {
    double rd = 1.0 / (double)W;
    float r = (float)rd;                  // fl32(1/W)
    double qd = (double)x * (double)r;    // exact product
    float q = (float)qd;                  // fl32(x*r)
    double pd = (double)q * (double)n;    // exact product
    float p = (float)pd;                  // fl32(q*n)
    return (int)p;                        // trunc
}

// K1: 16 rows x 128 cols per block, K-tile 32, 8 accs/thread.
__global__ __launch_bounds__(256) void gemm_u_kernel(
    const float* __restrict__ T, const float* __restrict__ W1,
    float* __restrict__ S, int P, int E, int npw)
{
    __shared__ float As[16][32];
    __shared__ float Bs[32][HD];

    int t = threadIdx.x;
    int c = t & 127;
    int rh = t >> 7;           // 0 or 1: rows rh*8 .. rh*8+7
    int row0 = blockIdx.x * 16;

    float acc[8];
#pragma unroll
    for (int r = 0; r < 8; ++r) acc[r] = 0.f;

    for (int k0 = 0; k0 < E; k0 += 32) {
#pragma unroll
        for (int i = 0; i < 2; ++i) {               // A tile 16x32
            int idx = t + i * 256;
            int r = idx >> 5, kk = idx & 31;
            int rg = row0 + r; if (rg >= P) rg = P - 1;
            As[r][kk] = T[(size_t)rg * E + k0 + kk];
        }
#pragma unroll
        for (int i = 0; i < 16; ++i) {              // B tile 32x128
            int idx = t + i * 256;
            int kk = idx >> 7, cc = idx & 127;
            Bs[kk][cc] = W1[(size_t)(k0 + kk) * HD + cc];
        }
        __syncthreads();
#pragma unroll
        for (int kk = 0; kk < 32; ++kk) {
            float bv = Bs[kk][c];
#pragma unroll
            for (int r = 0; r < 8; ++r)
                acc[r] += As[rh * 8 + r][kk] * bv;
        }
        __syncthreads();
    }

    // Scatter into SAT interior: p -> S[1 + p/npw][1 + p%npw][c]
#pragma unroll
    for (int r = 0; r < 8; ++r) {
        int p = row0 + rh * 8 + r;
        if (p < P) {
            int py = p / npw;
            int px = p - py * npw;
            S[((size_t)(py + 1) * (npw + 1) + (px + 1)) * HD + c] = acc[r];
        }
    }
}

__global__ __launch_bounds__(HD) void prefix_x_kernel(
    float* __restrict__ S, int npw)
{
    int y = blockIdx.x + 1;            // 1..nph
    int e = threadIdx.x;               // 0..127
    size_t row = (size_t)y * (size_t)(npw + 1);
    S[row * HD + e] = 0.f;             // col 0
    float acc = 0.f;
    for (int x = 1; x <= npw; ++x) {
        size_t idx = (row + (size_t)x) * HD + e;
        acc += S[idx];
        S[idx] = acc;
    }
}

__global__ __launch_bounds__(HD) void prefix_y_kernel(
    float* __restrict__ S, int npw, int nph)
{
    int x = blockIdx.x;                // 0..npw
    int e = threadIdx.x;
    size_t stride = (size_t)(npw + 1) * HD;
    size_t base = (size_t)x * HD + (size_t)e;
    S[base] = 0.f;                     // row 0
    float acc = 0.f;
    for (int y = 1; y <= nph; ++y) {
        size_t idx = base + (size_t)y * stride;
        acc += S[idx];
        S[idx] = acc;
    }
}

// K4: 16 boxes x 128 cols per block; fp32 output.
__global__ __launch_bounds__(256) void pool_proj_kernel(
    const float* __restrict__ S, const int* __restrict__ bboxes,
    const int* __restrict__ pH, const int* __restrict__ pW,
    const float* __restrict__ b1, const float* __restrict__ gamma,
    const float* __restrict__ beta, const float* __restrict__ W2,
    const float* __restrict__ b2, float* __restrict__ out,
    int Nb, int npw, int nph, int fbW, int fbH)
{
    __shared__ float hs[16][HD + 1];   // +1 pad for row-stat reads
    __shared__ float Bs[32][HD];
    __shared__ int   cI11[16], cI12[16], cI21[16], cI22[16];
    __shared__ float cCnt[16];
    __shared__ float mu_s[16], rs_s[16];

    int t = threadIdx.x;
    int c = t & 127;
    int rh = t >> 7;
    int row0 = blockIdx.x * 16;

    if (t < 16) {
        int b = row0 + t; if (b >= Nb) b = Nb - 1;
        int x1 = bboxes[b * 4 + 0];
        int y1 = bboxes[b * 4 + 1];
        int x2 = bboxes[b * 4 + 2];
        int y2 = bboxes[b * 4 + 3];
        int Wi = decode_dim(pW, fbW);
        int Hi = decode_dim(pH, fbH);
        // V4 coords: XLA reciprocal-multiply semantics, bit-exact.
        int px1 = coord_map(x1, Wi, npw);
        int px2 = coord_map(x2, Wi, npw);
        int py1 = coord_map(y1, Hi, nph);
        int py2 = coord_map(y2, Hi, nph);
        px1 = min(max(px1, 0), npw - 1);
        px2 = max(px1 + 1, min(px2, npw));
        py1 = min(max(py1, 0), nph - 1);
        py2 = max(py1 + 1, min(py2, nph));
        int st = npw + 1;
        cI11[t] = (py1 * st + px1) * HD;
        cI12[t] = (py1 * st + px2) * HD;
        cI21[t] = (py2 * st + px1) * HD;
        cI22[t] = (py2 * st + px2) * HD;
        cCnt[t] = (float)((py2 - py1) * (px2 - px1));
    }
    __syncthreads();

    // pooled h = SAT gather / cnt + b1
    float bias1 = b1[c];
    float hv[8];
#pragma unroll
    for (int r = 0; r < 8; ++r) {
        int row = rh * 8 + r;
        float s = S[cI22[row] + c] - S[cI12[row] + c]
                - S[cI21[row] + c] + S[cI11[row] + c];
        hv[r] = s / cCnt[row] + bias1;
        hs[row][c] = hv[r];
    }
    __syncthreads();

    if (t < 16) {
        float m = 0.f;
#pragma unroll 8
        for (int i = 0; i < HD; ++i) m += hs[t][i];
        m *= (1.0f / HD);
        float v = 0.f;
#pragma unroll 8
        for (int i = 0; i < HD; ++i) { float d = hs[t][i] - m; v += d * d; }
        v *= (1.0f / HD);
        mu_s[t] = m;
        rs_s[t] = rsqrtf(v + 1e-5f);
    }
    __syncthreads();

    float g = gamma[c], be = beta[c];
#pragma unroll
    for (int r = 0; r < 8; ++r) {
        int row = rh * 8 + r;
        float x = (hv[r] - mu_s[row]) * rs_s[row] * g + be;
        hs[row][c] = fmaxf(x, 0.f);
    }
    __syncthreads();

    // GEMM2: (16 x 128) @ (128 x 128)
    float bias2 = b2[c];
    float acc2[8];
#pragma unroll
    for (int r = 0; r < 8; ++r) acc2[r] = bias2;
    for (int k0 = 0; k0 < HD; k0 += 32) {
#pragma unroll
        for (int i = 0; i < 16; ++i) {
            int idx = t + i * 256;
            int kk = idx >> 7, cc = idx & 127;
            Bs[kk][cc] = W2[(size_t)(k0 + kk) * HD + cc];
        }
        __syncthreads();
#pragma unroll
        for (int kk = 0; kk < 32; ++kk) {
            float bv = Bs[kk][c];
#pragma unroll
            for (int r = 0; r < 8; ++r)
                acc2[r] += hs[rh * 8 + r][k0 + kk] * bv;
        }
        __syncthreads();
    }

#pragma unroll
    for (int r = 0; r < 8; ++r) {
        int rg = row0 + rh * 8 + r;
        if (rg < Nb) out[(size_t)rg * HD + c] = acc2[r];
    }
}

extern "C" void kernel_launch(void* const* d_in, const int* in_sizes, int n_in,
                              void* d_out, int out_size, void* d_ws, size_t ws_size,
                              hipStream_t stream) {
    // Input mapping verified rounds 2-11 (fp32 arrays at dict order, int32
    // boxes in [0,1036), H=W=1036, fp32 output, safe rows match np).
    int iT = 0, iB = 1, iH = 2, iW = 3, iW1 = 4, ib1 = 5, ig = 6, ibe = 7,
        iW2 = 8, ib2 = 9;
    bool has_scalars = (n_in >= 10 && in_sizes[2] == 1 && in_sizes[3] == 1);
    if (!has_scalars) { iW1 = 2; ib1 = 3; ig = 4; ibe = 5; iW2 = 6; ib2 = 7; }

    const float* tokens = (const float*)d_in[iT];
    const int*   bboxes = (const int*)d_in[iB];
    const int*   pH     = has_scalars ? (const int*)d_in[iH] : nullptr;
    const int*   pW     = has_scalars ? (const int*)d_in[iW] : nullptr;
    const float* W1     = (const float*)d_in[iW1];
    const float* b1     = (const float*)d_in[ib1];
    const float* gamma  = (const float*)d_in[ig];
    const float* beta   = (const float*)d_in[ibe];
    const float* W2     = (const float*)d_in[iW2];
    const float* b2     = (const float*)d_in[ib2];
    float* out = (float*)d_out;

    int Hd = in_sizes[ib1];               // 128
    int E  = in_sizes[iW1] / Hd;          // 1024
    int Nb = in_sizes[iB] / 4;            // 4096
    int P  = in_sizes[iT] / E;            // 5476
    int npw = 1;
    while ((npw + 1) * (npw + 1) <= P) ++npw;  // isqrt -> 74
    int nph = P / npw;
    (void)out_size; (void)ws_size;

    float* S = (float*)d_ws;   // (nph+1) x (npw+1) x HD f32 = 2.88 MB

    gemm_u_kernel<<<dim3((P + 15) / 16), dim3(256), 0, stream>>>(
        tokens, W1, S, P, E, npw);
    prefix_x_kernel<<<dim3(nph), dim3(HD), 0, stream>>>(S, npw);
    prefix_y_kernel<<<dim3(npw + 1), dim3(HD), 0, stream>>>(S, npw, nph);
    pool_proj_kernel<<<dim3((Nb + 15) / 16), dim3(256), 0, stream>>>(
        S, bboxes, pH, pW, b1, gamma, beta, W2, b2, out, Nb, npw, nph,
        14 * npw, 14 * nph);
}

// Round 13
// 142.996 us; speedup vs baseline: 1.7158x; 1.7158x over previous
//
#include <hip/hip_runtime.h>

// ---------------------------------------------------------------------------
// VisionEncoder (PASSING since R12, absmax 1.95e-3): project -> SAT -> fused
// pool/LN/GEMM2. V4 coordinate semantics (XLA reciprocal-multiply) verified.
//
// R13 perf restructure:
//   K1 gemm_u  : 64x128 tile, 8x4 micro-tile, split-K=4 -> 4 partial buffers
//                (344 blocks x 8 waves; was 343 x 4 waves with 9 scalar LDS
//                reads per 8 FMAs, VALUBusy 23%, 117 us)
//   K2 prefix_x: sum 4 partials (coalesced) + x-scan in LDS -> SAT rows
//   K3 prefix_y: column scan staged through LDS (was 74-deep dependent HBM
//                chain)
//   K4 pool_proj: UNCHANGED from the R12 passing version.
// ---------------------------------------------------------------------------

#define HD 128  // hidden dim (verified)

__device__ __forceinline__ int decode_dim(const int* p, int fallback) {
    if (p == nullptr) return fallback;
    int vi = *p;
    if (vi >= 1 && vi <= 1000000) return vi;
    float vf = __int_as_float(vi);
    if (vf >= 1.0f && vf <= 1000000.0f) return (int)vf;
    return fallback;
}

// V4 (verified R12): trunc( fl32( fl32(x * fl32(1/W)) * n ) ), emulated
// bit-exactly via f64; optnone so no fast-math rewrite can touch it.
__attribute__((noinline, optnone))
__device__ int coord_map(int x, int W, int n) {
    double rd = 1.0 / (double)W;
    float r = (float)rd;
    double qd = (double)x * (double)r;
    float q = (float)qd;
    double pd = (double)q * (double)n;
    float p = (float)pd;
    return (int)p;
}

// ---------------------------------------------------------------------------
// K1: U_ks[p][c] partial GEMM over K-chunk ks. Tile 64 rows x 128 cols.
// Thread t: tc = t&31 (4 cols), tr = t>>5 (8 rows). LDS A k-major for b128.
// ---------------------------------------------------------------------------
__global__ __launch_bounds__(256) void gemm_u_kernel(
    const float* __restrict__ T, const float* __restrict__ W1,
    float* __restrict__ U, int P, int E)
{
    __shared__ float As[32][64];    // [kk][row]
    __shared__ float Bs[32][HD];    // [kk][col]

    int t  = threadIdx.x;
    int tc = t & 31;                // thread-col: cols tc*4 .. tc*4+3
    int tr = t >> 5;                // thread-row: rows tr*8 .. tr*8+7
    int row0 = blockIdx.x * 64;
    int ks   = blockIdx.y;          // K-split index, chunk = E/4
    int kchunk = E >> 2;
    int kbase  = ks * kchunk;
    float* Uo = U + (size_t)ks * (size_t)P * HD;

    float acc[8][4];
#pragma unroll
    for (int r = 0; r < 8; ++r)
#pragma unroll
        for (int j = 0; j < 4; ++j) acc[r][j] = 0.f;

    // staging indices
    int arow = t >> 2;              // 0..63
    int akq  = (t & 3) * 8;         // 0,8,16,24
    int brow = t >> 5;              // 0..7  (+= 8 per i)
    int bc   = (t & 31) * 4;

    for (int kt = 0; kt < kchunk; kt += 32) {
        int k0 = kbase + kt;
        // ---- stage A: T[row0..row0+63][k0..k0+31] -> As[kk][row]
        {
            int rg = row0 + arow; if (rg >= P) rg = P - 1;
            const float* tp = T + (size_t)rg * E + k0 + akq;
            float4 v0 = *(const float4*)tp;
            float4 v1 = *(const float4*)(tp + 4);
            As[akq + 0][arow] = v0.x; As[akq + 1][arow] = v0.y;
            As[akq + 2][arow] = v0.z; As[akq + 3][arow] = v0.w;
            As[akq + 4][arow] = v1.x; As[akq + 5][arow] = v1.y;
            As[akq + 6][arow] = v1.z; As[akq + 7][arow] = v1.w;
        }
        // ---- stage B: W1[k0..k0+31][0..127] -> Bs[kk][c]
#pragma unroll
        for (int i = 0; i < 4; ++i) {
            int kk = brow + i * 8;
            *(float4*)&Bs[kk][bc] =
                *(const float4*)&W1[(size_t)(k0 + kk) * HD + bc];
        }
        __syncthreads();

#pragma unroll
        for (int kk = 0; kk < 32; ++kk) {
            float4 a0 = *(const float4*)&As[kk][tr * 8];
            float4 a1 = *(const float4*)&As[kk][tr * 8 + 4];
            float4 b  = *(const float4*)&Bs[kk][tc * 4];
            float av[8] = {a0.x, a0.y, a0.z, a0.w, a1.x, a1.y, a1.z, a1.w};
            float bv[4] = {b.x, b.y, b.z, b.w};
#pragma unroll
            for (int r = 0; r < 8; ++r)
#pragma unroll
                for (int j = 0; j < 4; ++j)
                    acc[r][j] += av[r] * bv[j];
        }
        __syncthreads();
    }

    // epilogue: U_ks[p][tc*4..+3]
#pragma unroll
    for (int r = 0; r < 8; ++r) {
        int p = row0 + tr * 8 + r;
        if (p < P) {
            float4 v = make_float4(acc[r][0], acc[r][1], acc[r][2], acc[r][3]);
            *(float4*)&Uo[(size_t)p * HD + tc * 4] = v;
        }
    }
}

// ---------------------------------------------------------------------------
// K2: block y in [0,nph): sum 4 partials of row y (74x128), x-scan, write SAT
// row y+1 (with col-0 border = 0).
// ---------------------------------------------------------------------------
__global__ __launch_bounds__(256) void prefix_x_kernel(
    const float* __restrict__ U, float* __restrict__ S,
    int P, int npw, int nph)
{
    extern __shared__ float tile[];            // npw*HD floats
    int t = threadIdx.x;
    int y = blockIdx.x;
    int rowlen = npw * HD;                     // 9472
    size_t ubase = (size_t)y * rowlen;
    size_t ustride = (size_t)P * HD;

    for (int j = t; j < rowlen / 4; j += 256) {
        const float4* p0 = (const float4*)(U + ubase) + j;
        const float4* p1 = (const float4*)(U + ustride + ubase) + j;
        const float4* p2 = (const float4*)(U + 2 * ustride + ubase) + j;
        const float4* p3 = (const float4*)(U + 3 * ustride + ubase) + j;
        float4 a = *p0, b = *p1, c = *p2, d = *p3;
        float4 s = make_float4(a.x + b.x + c.x + d.x, a.y + b.y + c.y + d.y,
                               a.z + b.z + c.z + d.z, a.w + b.w + c.w + d.w);
        ((float4*)tile)[j] = s;
    }
    __syncthreads();

    if (t < HD) {
        int c = t;
        size_t srow = (size_t)(y + 1) * (npw + 1) * HD;
        S[srow + c] = 0.f;                     // col-0 border
        float acc = 0.f;
        for (int x = 0; x < npw; ++x) {
            acc += tile[x * HD + c];
            S[srow + (size_t)(x + 1) * HD + c] = acc;
        }
    }
}

// ---------------------------------------------------------------------------
// K3: block x in [0,npw]: stage column x (y=1..nph) through LDS, y-scan,
// write back; also write row-0 border.
// ---------------------------------------------------------------------------
__global__ __launch_bounds__(256) void prefix_y_kernel(
    float* __restrict__ S, int npw, int nph)
{
    extern __shared__ float tile[];            // nph*HD floats
    int t = threadIdx.x;
    int x = blockIdx.x;
    size_t stride = (size_t)(npw + 1) * HD;
    size_t base = (size_t)x * HD;

    for (int j = t; j < nph * HD; j += 256) {
        int y = j >> 7, c = j & 127;
        tile[j] = S[base + (size_t)(y + 1) * stride + c];
    }
    __syncthreads();

    if (t < HD) {
        int c = t;
        S[base + c] = 0.f;                     // row-0 border
        float acc = 0.f;
        for (int y = 0; y < nph; ++y) {
            acc += tile[y * HD + c];
            S[base + (size_t)(y + 1) * stride + c] = acc;
        }
    }
}

// ---------------------------------------------------------------------------
// K4: UNCHANGED passing version. 16 boxes x 128 cols per block.
// ---------------------------------------------------------------------------
__global__ __launch_bounds__(256) void pool_proj_kernel(
    const float* __restrict__ S, const int* __restrict__ bboxes,
    const int* __restrict__ pH, const int* __restrict__ pW,
    const float* __restrict__ b1, const float* __restrict__ gamma,
    const float* __restrict__ beta, const float* __restrict__ W2,
    const float* __restrict__ b2, float* __restrict__ out,
    int Nb, int npw, int nph, int fbW, int fbH)
{
    __shared__ float hs[16][HD + 1];
    __shared__ float Bs[32][HD];
    __shared__ int   cI11[16], cI12[16], cI21[16], cI22[16];
    __shared__ float cCnt[16];
    __shared__ float mu_s[16], rs_s[16];

    int t = threadIdx.x;
    int c = t & 127;
    int rh = t >> 7;
    int row0 = blockIdx.x * 16;

    if (t < 16) {
        int b = row0 + t; if (b >= Nb) b = Nb - 1;
        int x1 = bboxes[b * 4 + 0];
        int y1 = bboxes[b * 4 + 1];
        int x2 = bboxes[b * 4 + 2];
        int y2 = bboxes[b * 4 + 3];
        int Wi = decode_dim(pW, fbW);
        int Hi = decode_dim(pH, fbH);
        int px1 = coord_map(x1, Wi, npw);
        int px2 = coord_map(x2, Wi, npw);
        int py1 = coord_map(y1, Hi, nph);
        int py2 = coord_map(y2, Hi, nph);
        px1 = min(max(px1, 0), npw - 1);
        px2 = max(px1 + 1, min(px2, npw));
        py1 = min(max(py1, 0), nph - 1);
        py2 = max(py1 + 1, min(py2, nph));
        int st = npw + 1;
        cI11[t] = (py1 * st + px1) * HD;
        cI12[t] = (py1 * st + px2) * HD;
        cI21[t] = (py2 * st + px1) * HD;
        cI22[t] = (py2 * st + px2) * HD;
        cCnt[t] = (float)((py2 - py1) * (px2 - px1));
    }
    __syncthreads();

    float bias1 = b1[c];
    float hv[8];
#pragma unroll
    for (int r = 0; r < 8; ++r) {
        int row = rh * 8 + r;
        float s = S[cI22[row] + c] - S[cI12[row] + c]
                - S[cI21[row] + c] + S[cI11[row] + c];
        hv[r] = s / cCnt[row] + bias1;
        hs[row][c] = hv[r];
    }
    __syncthreads();

    if (t < 16) {
        float m = 0.f;
#pragma unroll 8
        for (int i = 0; i < HD; ++i) m += hs[t][i];
        m *= (1.0f / HD);
        float v = 0.f;
#pragma unroll 8
        for (int i = 0; i < HD; ++i) { float d = hs[t][i] - m; v += d * d; }
        v *= (1.0f / HD);
        mu_s[t] = m;
        rs_s[t] = rsqrtf(v + 1e-5f);
    }
    __syncthreads();

    float g = gamma[c], be = beta[c];
#pragma unroll
    for (int r = 0; r < 8; ++r) {
        int row = rh * 8 + r;
        float x = (hv[r] - mu_s[row]) * rs_s[row] * g + be;
        hs[row][c] = fmaxf(x, 0.f);
    }
    __syncthreads();

    float bias2 = b2[c];
    float acc2[8];
#pragma unroll
    for (int r = 0; r < 8; ++r) acc2[r] = bias2;
    for (int k0 = 0; k0 < HD; k0 += 32) {
#pragma unroll
        for (int i = 0; i < 16; ++i) {
            int idx = t + i * 256;
            int kk = idx >> 7, cc = idx & 127;
            Bs[kk][cc] = W2[(size_t)(k0 + kk) * HD + cc];
        }
        __syncthreads();
#pragma unroll
        for (int kk = 0; kk < 32; ++kk) {
            float bv = Bs[kk][c];
#pragma unroll
            for (int r = 0; r < 8; ++r)
                acc2[r] += hs[rh * 8 + r][k0 + kk] * bv;
        }
        __syncthreads();
    }

#pragma unroll
    for (int r = 0; r < 8; ++r) {
        int rg = row0 + rh * 8 + r;
        if (rg < Nb) out[(size_t)rg * HD + c] = acc2[r];
    }
}

extern "C" void kernel_launch(void* const* d_in, const int* in_sizes, int n_in,
                              void* d_out, int out_size, void* d_ws, size_t ws_size,
                              hipStream_t stream) {
    int iT = 0, iB = 1, iH = 2, iW = 3, iW1 = 4, ib1 = 5, ig = 6, ibe = 7,
        iW2 = 8, ib2 = 9;
    bool has_scalars = (n_in >= 10 && in_sizes[2] == 1 && in_sizes[3] == 1);
    if (!has_scalars) { iW1 = 2; ib1 = 3; ig = 4; ibe = 5; iW2 = 6; ib2 = 7; }

    const float* tokens = (const float*)d_in[iT];
    const int*   bboxes = (const int*)d_in[iB];
    const int*   pH     = has_scalars ? (const int*)d_in[iH] : nullptr;
    const int*   pW     = has_scalars ? (const int*)d_in[iW] : nullptr;
    const float* W1     = (const float*)d_in[iW1];
    const float* b1     = (const float*)d_in[ib1];
    const float* gamma  = (const float*)d_in[ig];
    const float* beta   = (const float*)d_in[ibe];
    const float* W2     = (const float*)d_in[iW2];
    const float* b2     = (const float*)d_in[ib2];
    float* out = (float*)d_out;

    int Hd = in_sizes[ib1];               // 128
    int E  = in_sizes[iW1] / Hd;          // 1024
    int Nb = in_sizes[iB] / 4;            // 4096
    int P  = in_sizes[iT] / E;            // 5476
    int npw = 1;
    while ((npw + 1) * (npw + 1) <= P) ++npw;  // 74
    int nph = P / npw;
    (void)out_size; (void)ws_size;

    // Workspace: S (75*75*128 f32 = 2.88 MB) then 4 partial U buffers
    // (4 * P*128 f32 = 11.2 MB). Total 14.1 MB (< 16.8 MB proven in R7).
    float* S = (float*)d_ws;
    size_t s_elems = ((size_t)(nph + 1) * (npw + 1) * HD + 255) & ~(size_t)255;
    float* U = S + s_elems;

    int mtiles = (P + 63) / 64;
    gemm_u_kernel<<<dim3(mtiles, 4), dim3(256), 0, stream>>>(
        tokens, W1, U, P, E);
    prefix_x_kernel<<<dim3(nph), dim3(256), (size_t)npw * HD * 4, stream>>>(
        U, S, P, npw, nph);
    prefix_y_kernel<<<dim3(npw + 1), dim3(256), (size_t)nph * HD * 4, stream>>>(
        S, npw, nph);
    pool_proj_kernel<<<dim3((Nb + 15) / 16), dim3(256), 0, stream>>>(
        S, bboxes, pH, pW, b1, gamma, beta, W2, b2, out, Nb, npw, nph,
        14 * npw, 14 * nph);
}

// Round 14
// 137.801 us; speedup vs baseline: 1.7804x; 1.0377x over previous
//
#include <hip/hip_runtime.h>

// ---------------------------------------------------------------------------
// VisionEncoder (PASSING since R12, absmax 1.95e-3): project -> SAT -> fused
// pool/LN/GEMM2. V4 coordinate semantics (XLA reciprocal-multiply) verified.
//
// R14: occupancy push.
//   K1 gemm_u  : 64x128 tile, 8x4 micro, split-K=8 -> 688 blocks (was 344,
//                Occ 11.6%, VALUBusy 23%); As padded to 65 (bank-conflict fix)
//   K2 prefix_x: grid (nph,2), 64 ch/block, sums 8 partials, x-scan -> SAT
//   K3 prefix_y: grid (npw+1,2), 64 ch/block, y-scan in LDS
//   K4 pool_proj: parallel LN stats (256-thr partial sums + LDS tree)
// ---------------------------------------------------------------------------

#define HD 128
#define SPLITK 8

__device__ __forceinline__ int decode_dim(const int* p, int fallback) {
    if (p == nullptr) return fallback;
    int vi = *p;
    if (vi >= 1 && vi <= 1000000) return vi;
    float vf = __int_as_float(vi);
    if (vf >= 1.0f && vf <= 1000000.0f) return (int)vf;
    return fallback;
}

// V4 (verified R12): trunc( fl32( fl32(x * fl32(1/W)) * n ) ), bit-exact via
// f64; optnone so no fast-math rewrite can touch it.
__attribute__((noinline, optnone))
__device__ int coord_map(int x, int W, int n) {
    double rd = 1.0 / (double)W;
    float r = (float)rd;
    double qd = (double)x * (double)r;
    float q = (float)qd;
    double pd = (double)q * (double)n;
    float p = (float)pd;
    return (int)p;
}

// ---------------------------------------------------------------------------
// K1: partial GEMM, tile 64 rows x 128 cols, K-chunk = E/8.
// ---------------------------------------------------------------------------
__global__ __launch_bounds__(256) void gemm_u_kernel(
    const float* __restrict__ T, const float* __restrict__ W1,
    float* __restrict__ U, int P, int E)
{
    __shared__ float As[32][65];    // [kk][row], pad 65: staging writes 2-way
    __shared__ float Bs[32][HD];    // [kk][col]

    int t  = threadIdx.x;
    int tc = t & 31;                // cols tc*4 .. tc*4+3
    int tr = t >> 5;                // rows tr*8 .. tr*8+7
    int row0 = blockIdx.x * 64;
    int ks   = blockIdx.y;
    int kchunk = E >> 3;            // 128
    int kbase  = ks * kchunk;
    float* Uo = U + (size_t)ks * (size_t)P * HD;

    float acc[8][4];
#pragma unroll
    for (int r = 0; r < 8; ++r)
#pragma unroll
        for (int j = 0; j < 4; ++j) acc[r][j] = 0.f;

    int arow = t >> 2;              // 0..63
    int akq  = (t & 3) * 8;         // 0,8,16,24
    int brow = t >> 5;              // 0..7
    int bc   = (t & 31) * 4;

    for (int kt = 0; kt < kchunk; kt += 32) {
        int k0 = kbase + kt;
        {   // stage A: T[row0+arow][k0+akq..+7] -> As[k][row]
            int rg = row0 + arow; if (rg >= P) rg = P - 1;
            const float* tp = T + (size_t)rg * E + k0 + akq;
            float4 v0 = *(const float4*)tp;
            float4 v1 = *(const float4*)(tp + 4);
            As[akq + 0][arow] = v0.x; As[akq + 1][arow] = v0.y;
            As[akq + 2][arow] = v0.z; As[akq + 3][arow] = v0.w;
            As[akq + 4][arow] = v1.x; As[akq + 5][arow] = v1.y;
            As[akq + 6][arow] = v1.z; As[akq + 7][arow] = v1.w;
        }
#pragma unroll
        for (int i = 0; i < 4; ++i) {   // stage B
            int kk = brow + i * 8;
            *(float4*)&Bs[kk][bc] =
                *(const float4*)&W1[(size_t)(k0 + kk) * HD + bc];
        }
        __syncthreads();

#pragma unroll
        for (int kk = 0; kk < 32; ++kk) {
            float4 a0 = *(const float4*)&As[kk][tr * 8];
            float4 a1 = *(const float4*)&As[kk][tr * 8 + 4];
            float4 b  = *(const float4*)&Bs[kk][tc * 4];
            float av[8] = {a0.x, a0.y, a0.z, a0.w, a1.x, a1.y, a1.z, a1.w};
            float bv[4] = {b.x, b.y, b.z, b.w};
#pragma unroll
            for (int r = 0; r < 8; ++r)
#pragma unroll
                for (int j = 0; j < 4; ++j)
                    acc[r][j] += av[r] * bv[j];
        }
        __syncthreads();
    }

#pragma unroll
    for (int r = 0; r < 8; ++r) {
        int p = row0 + tr * 8 + r;
        if (p < P) {
            float4 v = make_float4(acc[r][0], acc[r][1], acc[r][2], acc[r][3]);
            *(float4*)&Uo[(size_t)p * HD + tc * 4] = v;
        }
    }
}

// ---------------------------------------------------------------------------
// K2: block (y, chalf): sum SPLITK partials of row y (74 x 64ch), x-scan,
// write SAT row y+1 (+ col-0 border).
// ---------------------------------------------------------------------------
__global__ __launch_bounds__(256) void prefix_x_kernel(
    const float* __restrict__ U, float* __restrict__ S,
    int P, int npw, int nph)
{
    extern __shared__ float tile[];            // npw*64 floats
    int t = threadIdx.x;
    int y = blockIdx.x;
    int ch0 = blockIdx.y * 64;
    size_t ustride = (size_t)P * HD;
    size_t ubase = (size_t)y * npw * HD + ch0;

    int nj = npw * 16;                         // float4 groups
    for (int j = t; j < nj; j += 256) {
        int x = j >> 4, cq = (j & 15) * 4;
        size_t off = ubase + (size_t)x * HD + cq;
        float4 s = *(const float4*)(U + off);
#pragma unroll
        for (int p = 1; p < SPLITK; ++p) {
            float4 v = *(const float4*)(U + (size_t)p * ustride + off);
            s.x += v.x; s.y += v.y; s.z += v.z; s.w += v.w;
        }
        *(float4*)&tile[x * 64 + cq] = s;
    }
    __syncthreads();

    if (t < 64) {
        int c = t;
        size_t srow = (size_t)(y + 1) * (npw + 1) * HD + ch0;
        S[srow + c] = 0.f;                     // col-0 border
        float acc = 0.f;
        for (int x = 0; x < npw; ++x) {
            acc += tile[x * 64 + c];
            S[srow + (size_t)(x + 1) * HD + c] = acc;
        }
    }
}

// ---------------------------------------------------------------------------
// K3: block (x, chalf): stage column x (y=1..nph) through LDS, y-scan,
// write back (+ row-0 border).
// ---------------------------------------------------------------------------
__global__ __launch_bounds__(256) void prefix_y_kernel(
    float* __restrict__ S, int npw, int nph)
{
    extern __shared__ float tile[];            // nph*64 floats
    int t = threadIdx.x;
    int x = blockIdx.x;
    int ch0 = blockIdx.y * 64;
    size_t stride = (size_t)(npw + 1) * HD;
    size_t base = (size_t)x * HD + ch0;

    int nj = nph * 16;
    for (int j = t; j < nj; j += 256) {
        int y = j >> 4, cq = (j & 15) * 4;
        *(float4*)&tile[y * 64 + cq] =
            *(const float4*)(S + base + (size_t)(y + 1) * stride + cq);
    }
    __syncthreads();

    if (t < 64) {
        int c = t;
        S[base + c] = 0.f;                     // row-0 border
        float acc = 0.f;
        for (int y = 0; y < nph; ++y) {
            acc += tile[y * 64 + c];
            S[base + (size_t)(y + 1) * stride + c] = acc;
        }
    }
}

// ---------------------------------------------------------------------------
// K4: 16 boxes x 128 cols; parallel LN stats; fp32 out.
// ---------------------------------------------------------------------------
__global__ __launch_bounds__(256) void pool_proj_kernel(
    const float* __restrict__ S, const int* __restrict__ bboxes,
    const int* __restrict__ pH, const int* __restrict__ pW,
    const float* __restrict__ b1, const float* __restrict__ gamma,
    const float* __restrict__ beta, const float* __restrict__ W2,
    const float* __restrict__ b2, float* __restrict__ out,
    int Nb, int npw, int nph, int fbW, int fbH)
{
    __shared__ float hs[16][HD + 1];
    __shared__ float Bs[32][HD];
    __shared__ float red_s[16][17], red_q[16][17];
    __shared__ int   cI11[16], cI12[16], cI21[16], cI22[16];
    __shared__ float cCnt[16];
    __shared__ float mu_s[16], rs_s[16];

    int t = threadIdx.x;
    int c = t & 127;
    int rh = t >> 7;
    int row0 = blockIdx.x * 16;

    if (t < 16) {
        int b = row0 + t; if (b >= Nb) b = Nb - 1;
        int x1 = bboxes[b * 4 + 0];
        int y1 = bboxes[b * 4 + 1];
        int x2 = bboxes[b * 4 + 2];
        int y2 = bboxes[b * 4 + 3];
        int Wi = decode_dim(pW, fbW);
        int Hi = decode_dim(pH, fbH);
        int px1 = coord_map(x1, Wi, npw);
        int px2 = coord_map(x2, Wi, npw);
        int py1 = coord_map(y1, Hi, nph);
        int py2 = coord_map(y2, Hi, nph);
        px1 = min(max(px1, 0), npw - 1);
        px2 = max(px1 + 1, min(px2, npw));
        py1 = min(max(py1, 0), nph - 1);
        py2 = max(py1 + 1, min(py2, nph));
        int st = npw + 1;
        cI11[t] = (py1 * st + px1) * HD;
        cI12[t] = (py1 * st + px2) * HD;
        cI21[t] = (py2 * st + px1) * HD;
        cI22[t] = (py2 * st + px2) * HD;
        cCnt[t] = (float)((py2 - py1) * (px2 - px1));
    }
    __syncthreads();

    float bias1 = b1[c];
    float hv[8];
#pragma unroll
    for (int r = 0; r < 8; ++r) {
        int row = rh * 8 + r;
        float s = S[cI22[row] + c] - S[cI12[row] + c]
                - S[cI21[row] + c] + S[cI11[row] + c];
        hv[r] = s / cCnt[row] + bias1;
        hs[row][c] = hv[r];
    }
    __syncthreads();

    // parallel LN stats: 16 threads per row, 8 elements each
    {
        int sr = t & 15;           // row
        int sg = t >> 4;           // group 0..15
        float ps = 0.f, pq = 0.f;
#pragma unroll
        for (int i = 0; i < 8; ++i) {
            float v = hs[sr][sg * 8 + i];
            ps += v; pq += v * v;
        }
        red_s[sr][sg] = ps; red_q[sr][sg] = pq;
    }
    __syncthreads();
    if (t < 16) {
        float s = 0.f, q = 0.f;
#pragma unroll
        for (int i = 0; i < 16; ++i) { s += red_s[t][i]; q += red_q[t][i]; }
        float m = s * (1.0f / HD);
        float v = q * (1.0f / HD) - m * m;
        mu_s[t] = m;
        rs_s[t] = rsqrtf(v + 1e-5f);
    }
    __syncthreads();

    float g = gamma[c], be = beta[c];
#pragma unroll
    for (int r = 0; r < 8; ++r) {
        int row = rh * 8 + r;
        float x = (hv[r] - mu_s[row]) * rs_s[row] * g + be;
        hs[row][c] = fmaxf(x, 0.f);
    }
    __syncthreads();

    float bias2 = b2[c];
    float acc2[8];
#pragma unroll
    for (int r = 0; r < 8; ++r) acc2[r] = bias2;
    for (int k0 = 0; k0 < HD; k0 += 32) {
#pragma unroll
        for (int i = 0; i < 16; ++i) {
            int idx = t + i * 256;
            int kk = idx >> 7, cc = idx & 127;
            Bs[kk][cc] = W2[(size_t)(k0 + kk) * HD + cc];
        }
        __syncthreads();
#pragma unroll
        for (int kk = 0; kk < 32; ++kk) {
            float bv = Bs[kk][c];
#pragma unroll
            for (int r = 0; r < 8; ++r)
                acc2[r] += hs[rh * 8 + r][k0 + kk] * bv;
        }
        __syncthreads();
    }

#pragma unroll
    for (int r = 0; r < 8; ++r) {
        int rg = row0 + rh * 8 + r;
        if (rg < Nb) out[(size_t)rg * HD + c] = acc2[r];
    }
}

extern "C" void kernel_launch(void* const* d_in, const int* in_sizes, int n_in,
                              void* d_out, int out_size, void* d_ws, size_t ws_size,
                              hipStream_t stream) {
    int iT = 0, iB = 1, iH = 2, iW = 3, iW1 = 4, ib1 = 5, ig = 6, ibe = 7,
        iW2 = 8, ib2 = 9;
    bool has_scalars = (n_in >= 10 && in_sizes[2] == 1 && in_sizes[3] == 1);
    if (!has_scalars) { iW1 = 2; ib1 = 3; ig = 4; ibe = 5; iW2 = 6; ib2 = 7; }

    const float* tokens = (const float*)d_in[iT];
    const int*   bboxes = (const int*)d_in[iB];
    const int*   pH     = has_scalars ? (const int*)d_in[iH] : nullptr;
    const int*   pW     = has_scalars ? (const int*)d_in[iW] : nullptr;
    const float* W1     = (const float*)d_in[iW1];
    const float* b1     = (const float*)d_in[ib1];
    const float* gamma  = (const float*)d_in[ig];
    const float* beta   = (const float*)d_in[ibe];
    const float* W2     = (const float*)d_in[iW2];
    const float* b2     = (const float*)d_in[ib2];
    float* out = (float*)d_out;

    int Hd = in_sizes[ib1];               // 128
    int E  = in_sizes[iW1] / Hd;          // 1024
    int Nb = in_sizes[iB] / 4;            // 4096
    int P  = in_sizes[iT] / E;            // 5476
    int npw = 1;
    while ((npw + 1) * (npw + 1) <= P) ++npw;  // 74
    int nph = P / npw;
    (void)out_size; (void)ws_size;

    // Workspace: S (2.88 MB) + 8 partial U buffers (22.4 MB) = 25.3 MB
    // (ws_size observed 256 MB via harness poison fill).
    float* S = (float*)d_ws;
    size_t s_elems = ((size_t)(nph + 1) * (npw + 1) * HD + 255) & ~(size_t)255;
    float* U = S + s_elems;

    int mtiles = (P + 63) / 64;
    gemm_u_kernel<<<dim3(mtiles, SPLITK), dim3(256), 0, stream>>>(
        tokens, W1, U, P, E);
    prefix_x_kernel<<<dim3(nph, 2), dim3(256), (size_t)npw * 64 * 4, stream>>>(
        U, S, P, npw, nph);
    prefix_y_kernel<<<dim3(npw + 1, 2), dim3(256), (size_t)nph * 64 * 4, stream>>>(
        S, npw, nph);
    pool_proj_kernel<<<dim3((Nb + 15) / 16), dim3(256), 0, stream>>>(
        S, bboxes, pH, pW, b1, gamma, beta, W2, b2, out, Nb, npw, nph,
        14 * npw, 14 * nph);
}